// Round 4
// baseline (269.850 us; speedup 1.0000x reference)
//
#include <hip/hip_runtime.h>
#include <stdint.h>

// ---------------------------------------------------------------------------
// B=32, C=4, S=256, L=256, Din=Dout=256
//   corr[b,s,t] = dot(fm[b,s,:], fm[b,t,:])
//   MLP 1->16->8->2 (exact GELU), hard gumbel-softmax (jax key 42, threefry,
//   partitionable), adj binary, diag=1, row-normalized;
//   X = adj @ F ; out = X @ Wl + bl
// corr kernel: 32x32 macro-tile, 2x2 outputs/thread, f32 LDS + f32 fast path
// with |margin| >= 1e-3 guard; f64 recompute (dot from LDS + MLP + gumbel)
// on guard failure -> decisions identical to the all-f64 path.
// ---------------------------------------------------------------------------

__device__ __forceinline__ void threefry2x32(uint32_t x0, uint32_t x1,
                                             uint32_t& o0, uint32_t& o1) {
  // key = (0, 42) from jax.random.key(42)
  const uint32_t ks0 = 0u;
  const uint32_t ks1 = 42u;
  const uint32_t ks2 = 0x1BD11BDAu ^ ks0 ^ ks1;
  const uint32_t ks[3] = {ks0, ks1, ks2};
  const uint32_t rot[2][4] = {{13u, 15u, 26u, 6u}, {17u, 29u, 16u, 24u}};
  x0 += ks0;
  x1 += ks1;
#pragma unroll
  for (int i = 0; i < 5; ++i) {
#pragma unroll
    for (int j = 0; j < 4; ++j) {
      const uint32_t r = rot[i & 1][j];
      x0 += x1;
      x1 = (x1 << r) | (x1 >> (32u - r));
      x1 ^= x0;
    }
    x0 += ks[(i + 1) % 3];
    x1 += ks[(i + 2) % 3] + (uint32_t)(i + 1);
  }
  o0 = x0;
  o1 = x1;
}

__device__ __forceinline__ float uniform_at(uint32_t j) {
  // partitionable threefry: ctr=(0,j), bits = o0^o1
  uint32_t o0, o1;
  threefry2x32(0u, j, o0, o1);
  const uint32_t bits = o0 ^ o1;
  uint32_t fb = (bits >> 9) | 0x3F800000u;
  float frac = __uint_as_float(fb) - 1.0f;
  return fmaxf(frac + 1e-10f, 1e-10f);
}

__device__ __forceinline__ double gumbel64_at(uint32_t j) {
  double t = -log((double)uniform_at(j));
  return -log(t);
}

__device__ __forceinline__ float gumbel32_at(uint32_t j) {
  float t = -logf(uniform_at(j));
  return -logf(t);
}

__device__ __forceinline__ double gelu_d(double x) {
  return 0.5 * x * (1.0 + erf(x * 0.70710678118654752440));
}

__device__ __forceinline__ float gelu_f(float x) {
  return 0.5f * x * (1.0f + erff(x * 0.70710678f));
}

// exact f64 dot over 256 f32 elements in LDS
__device__ __noinline__ double dot64(const float* __restrict__ Srow,
                                     const float* __restrict__ Trow) {
  double a0 = 0.0, a1 = 0.0, a2 = 0.0, a3 = 0.0;
  for (int k = 0; k < 256; k += 4) {
    a0 += (double)Srow[k + 0] * (double)Trow[k + 0];
    a1 += (double)Srow[k + 1] * (double)Trow[k + 1];
    a2 += (double)Srow[k + 2] * (double)Trow[k + 2];
    a3 += (double)Srow[k + 3] * (double)Trow[k + 3];
  }
  return (a0 + a2) + (a1 + a3);
}

// exact f64 MLP
__device__ __noinline__ void mlp64(double acc, const float* __restrict__ W1,
                                   const float* __restrict__ b1,
                                   const float* __restrict__ W2,
                                   const float* __restrict__ b2,
                                   const float* __restrict__ W3,
                                   const float* __restrict__ b3, double& l0,
                                   double& l1) {
  double h1[16];
#pragma unroll
  for (int i = 0; i < 16; ++i)
    h1[i] = gelu_d(acc * (double)W1[i] + (double)b1[i]);
  double h2[8];
#pragma unroll
  for (int j = 0; j < 8; ++j) {
    double v = (double)b2[j];
#pragma unroll
    for (int i = 0; i < 16; ++i) v += h1[i] * (double)W2[i * 8 + j];
    h2[j] = gelu_d(v);
  }
  l0 = (double)b3[0];
  l1 = (double)b3[1];
#pragma unroll
  for (int j = 0; j < 8; ++j) {
    l0 += h2[j] * (double)W3[j * 2 + 0];
    l1 += h2[j] * (double)W3[j * 2 + 1];
  }
}

// ---------------------------------------------------------------------------
// Kernel 1: corr + MLP + gumbel -> binary adj.
// grid (36, 32): x = upper-tri pair of 32-row macro-tiles (8x8 grid),
// y = batch. 256 threads; each computes a 2x2 block of dots (strided by 16)
// and 1-2 decisions per dot.
// ---------------------------------------------------------------------------
__global__ __launch_bounds__(256) void corr_adj_kernel(
    const float* __restrict__ fm,
    const float* __restrict__ W1, const float* __restrict__ b1,
    const float* __restrict__ W2, const float* __restrict__ b2,
    const float* __restrict__ W3, const float* __restrict__ b3,
    float* __restrict__ adj) {
  const int b = blockIdx.y;

  // decode upper-triangle pair (ti <= tj) from blockIdx.x in [0,36)
  int q = blockIdx.x, ti = 0;
  while (q >= 8 - ti) {
    q -= 8 - ti;
    ++ti;
  }
  const int tj = ti + q;
  const int s0 = ti * 32;
  const int t0 = tj * 32;
  const bool diag = (ti == tj);

  __shared__ float smS[32][260];  // pitch 260: bank stride 4 -> 2-way max
  __shared__ float smT[32][260];

  const int tid = threadIdx.x;
  {
    const float* baseS = fm + ((size_t)b * 256 + s0) * 256;
    const float* baseT = fm + ((size_t)b * 256 + t0) * 256;
#pragma unroll
    for (int p = 0; p < 8; ++p) {
      int idx = tid + p * 256;  // 0..2047 quads
      int r = idx >> 6;         // 0..31
      int c = (idx & 63) * 4;   // 0..252
      *(float4*)(&smS[r][c]) = *(const float4*)(baseS + r * 256 + c);
      if (!diag)
        *(float4*)(&smT[r][c]) = *(const float4*)(baseT + r * 256 + c);
    }
  }
  __syncthreads();

  const int i = tid >> 4;  // 0..15 : s sub-row
  const int j = tid & 15;  // 0..15 : t sub-row

  const float* S0 = smS[i];
  const float* S1 = smS[i + 16];
  const float* T0 = diag ? smS[j] : smT[j];
  const float* T1 = diag ? smS[j + 16] : smT[j + 16];

  float c00 = 0.f, c01 = 0.f, c10 = 0.f, c11 = 0.f;
#pragma unroll 4
  for (int k = 0; k < 256; k += 4) {
    float4 sa = *(const float4*)(S0 + k);
    float4 sb = *(const float4*)(S1 + k);
    float4 ta = *(const float4*)(T0 + k);
    float4 tb = *(const float4*)(T1 + k);
    c00 = fmaf(sa.x, ta.x, c00); c00 = fmaf(sa.y, ta.y, c00);
    c00 = fmaf(sa.z, ta.z, c00); c00 = fmaf(sa.w, ta.w, c00);
    c01 = fmaf(sa.x, tb.x, c01); c01 = fmaf(sa.y, tb.y, c01);
    c01 = fmaf(sa.z, tb.z, c01); c01 = fmaf(sa.w, tb.w, c01);
    c10 = fmaf(sb.x, ta.x, c10); c10 = fmaf(sb.y, ta.y, c10);
    c10 = fmaf(sb.z, ta.z, c10); c10 = fmaf(sb.w, ta.w, c10);
    c11 = fmaf(sb.x, tb.x, c11); c11 = fmaf(sb.y, tb.y, c11);
    c11 = fmaf(sb.z, tb.z, c11); c11 = fmaf(sb.w, tb.w, c11);
  }
  const float cf[2][2] = {{c00, c01}, {c10, c11}};

#pragma unroll
  for (int p = 0; p < 2; ++p) {
#pragma unroll
    for (int qq = 0; qq < 2; ++qq) {
      const int s = s0 + i + 16 * p;
      const int t = t0 + j + 16 * qq;
      const float corr = cf[p][qq];

      // f32 MLP -> dphi
      float h1[16];
#pragma unroll
      for (int u = 0; u < 16; ++u) h1[u] = gelu_f(fmaf(corr, W1[u], b1[u]));
      float h2[8];
#pragma unroll
      for (int v = 0; v < 8; ++v) {
        float x = b2[v];
#pragma unroll
        for (int u = 0; u < 16; ++u) x = fmaf(h1[u], W2[u * 8 + v], x);
        h2[v] = gelu_f(x);
      }
      float l0f = b3[0], l1f = b3[1];
#pragma unroll
      for (int v = 0; v < 8; ++v) {
        l0f = fmaf(h2[v], W3[v * 2 + 0], l0f);
        l1f = fmaf(h2[v], W3[v * 2 + 1], l1f);
      }
      const float dphi = l0f - l1f;

      const float* Srow = (p == 0) ? S0 : S1;
      const float* Trow = (qq == 0) ? T0 : T1;
      bool have = false;
      double l0e = 0.0, l1e = 0.0;

      // decision (s,t)
      {
        const uint32_t base =
            ((uint32_t)b << 16) | ((uint32_t)s << 8) | (uint32_t)t;
        float g0 = gumbel32_at(2u * base);
        float g1 = gumbel32_at(2u * base + 1u);
        float d = dphi - (g1 - g0);
        float a;
        if (fabsf(d) >= 1e-3f) {
          a = (d >= 0.0f) ? 1.0f : 0.0f;
        } else {
          if (!have) {
            mlp64(dot64(Srow, Trow), W1, b1, W2, b2, W3, b3, l0e, l1e);
            have = true;
          }
          double G0 = gumbel64_at(2u * base);
          double G1 = gumbel64_at(2u * base + 1u);
          a = (l0e + G0 >= l1e + G1) ? 1.0f : 0.0f;
        }
        if (t == s) a = 1.0f;
        adj[((size_t)b << 16) | ((uint32_t)s << 8) | (uint32_t)t] = a;
      }

      // mirror decision (t,s) — off-diagonal tile pairs only
      if (!diag) {
        const uint32_t base =
            ((uint32_t)b << 16) | ((uint32_t)t << 8) | (uint32_t)s;
        float g0 = gumbel32_at(2u * base);
        float g1 = gumbel32_at(2u * base + 1u);
        float d = dphi - (g1 - g0);
        float a;
        if (fabsf(d) >= 1e-3f) {
          a = (d >= 0.0f) ? 1.0f : 0.0f;
        } else {
          if (!have) {
            mlp64(dot64(Srow, Trow), W1, b1, W2, b2, W3, b3, l0e, l1e);
            have = true;
          }
          double G0 = gumbel64_at(2u * base);
          double G1 = gumbel64_at(2u * base + 1u);
          a = (l0e + G0 >= l1e + G1) ? 1.0f : 0.0f;
        }
        adj[((size_t)b << 16) | ((uint32_t)t << 8) | (uint32_t)s] = a;
      }
    }
  }
}

// ---------------------------------------------------------------------------
// Kernel 2: row-normalize adj in place. grid 8192 rows, 64 threads.
// ---------------------------------------------------------------------------
__global__ __launch_bounds__(64) void rownorm_kernel(float* __restrict__ adj) {
  const size_t row = blockIdx.x;
  float* p = adj + row * 256;
  const int lane = threadIdx.x;
  float4 v = ((const float4*)p)[lane];
  float sum = v.x + v.y + v.z + v.w;
#pragma unroll
  for (int off = 32; off; off >>= 1) sum += __shfl_xor(sum, off);
  const float r = 1.0f / sum;
  v.x *= r; v.y *= r; v.z *= r; v.w *= r;
  ((float4*)p)[lane] = v;
}

// ---------------------------------------------------------------------------
// Kernels 3/4: f32 GEMM, M=N=K=256 per batch z. BM=BN=128, BK=8, 256 thr.
// ---------------------------------------------------------------------------
__global__ __launch_bounds__(256) void gemm_kernel(
    const float* __restrict__ A, const float* __restrict__ B,
    const float* __restrict__ bias, float* __restrict__ C,
    int aDiv, int bShared) {
  const int z = blockIdx.z;
  const float* Ab = A + (size_t)(z / aDiv) * 65536;
  const float* Bb = bShared ? B : (B + (size_t)z * 65536);
  float* Cb = C + (size_t)z * 65536;

  const int row0 = blockIdx.y * 128;
  const int col0 = blockIdx.x * 128;

  __shared__ float As[8][132];
  __shared__ float Bs[8][132];

  const int tid = threadIdx.x;
  const int tx = tid & 15;
  const int ty = tid >> 4;

  float acc[2][2][4][4];
#pragma unroll
  for (int a = 0; a < 2; ++a)
#pragma unroll
    for (int bq = 0; bq < 2; ++bq)
#pragma unroll
      for (int i = 0; i < 4; ++i)
#pragma unroll
        for (int j = 0; j < 4; ++j) acc[a][bq][i][j] = 0.0f;

  for (int k0 = 0; k0 < 256; k0 += 8) {
    {
      int r = tid >> 1, c = (tid & 1) * 4;
      float4 v = *(const float4*)(Ab + (size_t)(row0 + r) * 256 + k0 + c);
      As[c + 0][r] = v.x;
      As[c + 1][r] = v.y;
      As[c + 2][r] = v.z;
      As[c + 3][r] = v.w;
    }
    {
      int r = tid >> 5, c = (tid & 31) * 4;
      *(float4*)(&Bs[r][c]) =
          *(const float4*)(Bb + (size_t)(k0 + r) * 256 + col0 + c);
    }
    __syncthreads();

#pragma unroll
    for (int kk = 0; kk < 8; ++kk) {
      float a0[4], a1[4], b0[4], b1[4];
      *(float4*)a0 = *(const float4*)(&As[kk][ty * 4]);
      *(float4*)a1 = *(const float4*)(&As[kk][ty * 4 + 64]);
      *(float4*)b0 = *(const float4*)(&Bs[kk][tx * 4]);
      *(float4*)b1 = *(const float4*)(&Bs[kk][tx * 4 + 64]);
#pragma unroll
      for (int i = 0; i < 4; ++i)
#pragma unroll
        for (int j = 0; j < 4; ++j) {
          acc[0][0][i][j] += a0[i] * b0[j];
          acc[0][1][i][j] += a0[i] * b1[j];
          acc[1][0][i][j] += a1[i] * b0[j];
          acc[1][1][i][j] += a1[i] * b1[j];
        }
    }
    __syncthreads();
  }

#pragma unroll
  for (int ih = 0; ih < 2; ++ih)
#pragma unroll
    for (int i = 0; i < 4; ++i) {
      const int row = row0 + ih * 64 + ty * 4 + i;
#pragma unroll
      for (int jh = 0; jh < 2; ++jh) {
        const int col = col0 + jh * 64 + tx * 4;
        float4 o;
        o.x = acc[ih][jh][i][0];
        o.y = acc[ih][jh][i][1];
        o.z = acc[ih][jh][i][2];
        o.w = acc[ih][jh][i][3];
        if (bias) {
          float4 bv = *(const float4*)(bias + col);
          o.x += bv.x; o.y += bv.y; o.z += bv.z; o.w += bv.w;
        }
        *(float4*)(Cb + (size_t)row * 256 + col) = o;
      }
    }
}

extern "C" void kernel_launch(void* const* d_in, const int* in_sizes, int n_in,
                              void* d_out, int out_size, void* d_ws,
                              size_t ws_size, hipStream_t stream) {
  const float* features = (const float*)d_in[0];
  const float* fm       = (const float*)d_in[1];
  const float* W1 = (const float*)d_in[2];
  const float* b1 = (const float*)d_in[3];
  const float* W2 = (const float*)d_in[4];
  const float* b2 = (const float*)d_in[5];
  const float* W3 = (const float*)d_in[6];
  const float* b3 = (const float*)d_in[7];
  const float* Wl = (const float*)d_in[8];
  const float* bl = (const float*)d_in[9];
  float* out = (float*)d_out;

  float* adj = (float*)d_ws;                          // 8.4 MB
  float* X = (float*)d_ws + (size_t)32 * 256 * 256;   // 33.5 MB

  corr_adj_kernel<<<dim3(36, 32), 256, 0, stream>>>(fm, W1, b1, W2, b2, W3,
                                                    b3, adj);
  rownorm_kernel<<<dim3(8192), 64, 0, stream>>>(adj);
  gemm_kernel<<<dim3(2, 2, 128), 256, 0, stream>>>(adj, features, nullptr, X,
                                                   4, 0);
  gemm_kernel<<<dim3(2, 2, 128), 256, 0, stream>>>(X, Wl, bl, out, 1, 1);
}